// Round 1
// baseline (142.413 us; speedup 1.0000x reference)
//
#include <hip/hip_runtime.h>

#define NG 4096
#define RELAX 0.1875f
#define CHUNK 512
#define EV_THREADS 512

__device__ __forceinline__ float linf(int i) { return -1.0f + (2.0f/63.0f)*(float)i; }
// center-first axis permutation: {7,8,6,9,5,10,4,11,3,12,2,13,1,14,0,15}
__device__ __forceinline__ int cperm(int i) { return (i & 1) ? 7 + ((i+1)>>1) : 7 - (i>>1); }

// ---- A: fused reduce + transform ----
// Each of 8 blocks redundantly computes the full masked min/max (64 KB scan,
// deterministic & identical across blocks), then transforms its own 512 gaussians.
// Replaces gm_reduce1 + gm_reduce2 + gm_transform (3 launches -> 1).
__global__ __launch_bounds__(512) void gm_prep(
    const float* __restrict__ xyz, const float* __restrict__ scal,
    const float* __restrict__ rot, const float* __restrict__ opac,
    float4* __restrict__ posopa, float4* __restrict__ invrec)
{
  __shared__ float s_mn[3][512];
  __shared__ float s_mx[3][512];
  const int tid = threadIdx.x;
  float mn0=1e10f, mn1=1e10f, mn2=1e10f;
  float mx0=-1e10f, mx1=-1e10f, mx2=-1e10f;
  #pragma unroll
  for (int t = 0; t < NG/512; ++t) {
    int g = t*512 + tid;
    float o = opac[g];
    float sig = 1.0f/(1.0f + __expf(-o));
    bool keep = sig > 0.005f;
    float x = xyz[3*g+0], y = xyz[3*g+1], z = xyz[3*g+2];
    if (keep) {
      mn0 = fminf(mn0, x); mn1 = fminf(mn1, y); mn2 = fminf(mn2, z);
      mx0 = fmaxf(mx0, x); mx1 = fmaxf(mx1, y); mx2 = fmaxf(mx2, z);
    }
  }
  s_mn[0][tid]=mn0; s_mn[1][tid]=mn1; s_mn[2][tid]=mn2;
  s_mx[0][tid]=mx0; s_mx[1][tid]=mx1; s_mx[2][tid]=mx2;
  __syncthreads();
  for (int s = 256; s > 0; s >>= 1) {
    if (tid < s) {
      #pragma unroll
      for (int k = 0; k < 3; ++k) {
        s_mn[k][tid] = fminf(s_mn[k][tid], s_mn[k][tid+s]);
        s_mx[k][tid] = fmaxf(s_mx[k][tid], s_mx[k][tid+s]);
      }
    }
    __syncthreads();
  }
  const float cx = (s_mn[0][0]+s_mx[0][0])*0.5f;
  const float cy = (s_mn[1][0]+s_mx[1][0])*0.5f;
  const float cz = (s_mn[2][0]+s_mx[2][0])*0.5f;
  const float rmax = fmaxf(s_mx[0][0]-s_mn[0][0],
                     fmaxf(s_mx[1][0]-s_mn[1][0], s_mx[2][0]-s_mn[2][0]));
  const float sc = 1.8f/rmax;

  const int g = blockIdx.x*512 + tid;
  float o = opac[g];
  float sig = 1.0f/(1.0f + __expf(-o));
  float opa = (sig > 0.005f) ? sig : 0.0f;
  float xs = (xyz[3*g+0]-cx)*sc;
  float ys = (xyz[3*g+1]-cy)*sc;
  float zs = (xyz[3*g+2]-cz)*sc;
  float sdx = __expf(scal[3*g+0])*sc;
  float sdy = __expf(scal[3*g+1])*sc;
  float sdz = __expf(scal[3*g+2])*sc;
  float qr=rot[4*g+0], qx=rot[4*g+1], qy=rot[4*g+2], qz=rot[4*g+3];
  float qn = 1.0f/sqrtf(qr*qr+qx*qx+qy*qy+qz*qz);
  qr*=qn; qx*=qn; qy*=qn; qz*=qn;
  float R00 = 1.0f-2.0f*(qy*qy+qz*qz), R01 = 2.0f*(qx*qy-qr*qz), R02 = 2.0f*(qx*qz+qr*qy);
  float R10 = 2.0f*(qx*qy+qr*qz), R11 = 1.0f-2.0f*(qx*qx+qz*qz), R12 = 2.0f*(qy*qz-qr*qx);
  float R20 = 2.0f*(qx*qz-qr*qy), R21 = 2.0f*(qy*qz+qr*qx), R22 = 1.0f-2.0f*(qx*qx+qy*qy);
  float L00=R00*sdx, L01=R01*sdy, L02=R02*sdz;
  float L10=R10*sdx, L11=R11*sdy, L12=R12*sdz;
  float L20=R20*sdx, L21=R21*sdy, L22=R22*sdz;
  float a = L00*L00+L01*L01+L02*L02;
  float b = L00*L10+L01*L11+L02*L12;
  float cc= L00*L20+L01*L21+L02*L22;
  float d = L10*L10+L11*L11+L12*L12;
  float e = L10*L20+L11*L21+L12*L22;
  float f = L20*L20+L21*L21+L22*L22;
  float det = a*d*f + 2.0f*e*cc*b - e*e*a - cc*cc*d - b*b*f + 1e-24f;
  float idt = 1.0f/det;
  float ia=(d*f-e*e)*idt, ib=(e*cc-b*f)*idt, ic=(e*b-cc*d)*idt;
  float id=(a*f-cc*cc)*idt, ie=(b*cc-e*a)*idt, iff=(a*d-b*b)*idt;
  posopa[g] = make_float4(xs, ys, zs, opa);
  invrec[2*g+0] = make_float4(-0.5f*ia, -ib, -ic, -0.5f*id);
  invrec[2*g+1] = make_float4(-ie, -0.5f*iff, 0.0f, 0.0f);
}

// ---- B: full 3D (bi,bj,bk) binning ----
// 256 blocks = (bi,bj). Each scans all 4096 once with the x,y window test,
// then scatters survivors into the 16 per-bk sublists (LDS counters, so no
// global zeroing needed). Eval then stages exactly its record set.
__global__ __launch_bounds__(256) void gm_bin3(
    const float4* __restrict__ posopa,
    int* __restrict__ bincnt, unsigned short* __restrict__ binidx, int cap)
{
  __shared__ int s_cnt[16];
  const int tid = threadIdx.x;
  const int b = blockIdx.x;           // bi*16+bj
  const int bi = b >> 4, bj = b & 15;
  const float vminx = linf(bi*4) - RELAX, vmaxx = linf(bi*4+3) + RELAX;
  const float vminy = linf(bj*4) - RELAX, vmaxy = linf(bj*4+3) + RELAX;
  if (tid < 16) s_cnt[tid] = 0;
  __syncthreads();
  #pragma unroll
  for (int t = 0; t < NG/256; ++t) {
    int g = t*256 + tid;
    float4 P = posopa[g];
    if (P.w > 0.0f &&
        P.x > vminx && P.x < vmaxx &&
        P.y > vminy && P.y < vmaxy) {
      #pragma unroll
      for (int bk = 0; bk < 16; ++bk) {
        const float lo = linf(bk*4) - RELAX, hi = linf(bk*4+3) + RELAX;
        if (P.z > lo && P.z < hi) {
          int slot = atomicAdd(&s_cnt[bk], 1);
          if (slot < cap)
            binidx[(size_t)((b<<4) + bk)*cap + slot] = (unsigned short)g;
        }
      }
    }
  }
  __syncthreads();
  if (tid < 16) bincnt[(b<<4) + tid] = min(s_cnt[tid], cap);
}

// ---- C: eval from exact 3D bin list (no filter, no atomics in staging) ----
__global__ __launch_bounds__(EV_THREADS) void gm_evaluate(
    const float4* __restrict__ posopa, const float4* __restrict__ invrec,
    const int* __restrict__ bincnt, const unsigned short* __restrict__ binidx,
    int cap, float* __restrict__ out)
{
  __shared__ float4 s_g[CHUNK*3];       // 24 KB
  __shared__ float  s_acc[EV_THREADS];  // 2 KB
  const int tid = threadIdx.x;
  const int b = blockIdx.x;
  const int bi = cperm(b >> 8), bj = cperm((b >> 4) & 15), bk = cperm(b & 15);
  const int bin = (bi*16 + bj)*16 + bk;
  const int p    = tid & 63;
  const int part = tid >> 6;            // 0..7
  const int sx = p >> 4, sy = (p >> 2) & 3, sz = p & 3;
  const float ptx = linf(bi*4+sx), pty = linf(bj*4+sy), ptz = linf(bk*4+sz);
  const unsigned short* mylist = binidx + (size_t)bin*cap;
  const int n = bincnt[bin];
  float acc = 0.0f;

  for (int c0 = 0; c0 < n; c0 += CHUNK) {
    const int lim = min(n - c0, CHUNK);
    if (tid < lim) {                    // EV_THREADS == CHUNK: 1 record/thread
      int g = mylist[c0 + tid];
      s_g[3*tid+0] = posopa[g];
      s_g[3*tid+1] = invrec[2*g+0];
      s_g[3*tid+2] = invrec[2*g+1];
    }
    __syncthreads();
    #pragma unroll 4
    for (int j = part; j < lim; j += 8) {
      float4 P  = s_g[3*j+0];
      float4 I0 = s_g[3*j+1];
      float4 I1 = s_g[3*j+2];
      float px = ptx - P.x, py = pty - P.y, pz = ptz - P.z;
      float power = px*px*I0.x + py*py*I0.w + pz*pz*I1.y
                  + px*py*I0.y + px*pz*I0.z + py*pz*I1.x;
      power = (power > 0.0f) ? -1e10f : power;   // branchless
      acc += P.w * __expf(power);
    }
    __syncthreads();
  }

  s_acc[tid] = acc;
  __syncthreads();
  if (tid < 64) {
    float v = 0.0f;
    #pragma unroll
    for (int w = 0; w < 8; ++w) v += s_acc[tid + w*64];
    out[(bi*4+sx)*4096 + (bj*4+sy)*64 + (bk*4+sz)] = v;
  }
}

// ---- fallback eval (no binning) if ws is too small ----
__global__ __launch_bounds__(EV_THREADS) void gm_evaluate_nobin(
    const float4* __restrict__ posopa, const float4* __restrict__ invrec,
    float* __restrict__ out)
{
  __shared__ int    s_cnt;
  __shared__ float4 s_g[CHUNK*3];
  __shared__ float  s_acc[EV_THREADS];
  const int tid = threadIdx.x;
  const int b = blockIdx.x;
  const int bi = cperm(b >> 8), bj = cperm((b >> 4) & 15), bk = cperm(b & 15);
  const float vminx = linf(bi*4) - RELAX, vmaxx = linf(bi*4+3) + RELAX;
  const float vminy = linf(bj*4) - RELAX, vmaxy = linf(bj*4+3) + RELAX;
  const float vminz = linf(bk*4) - RELAX, vmaxz = linf(bk*4+3) + RELAX;
  const int p    = tid & 63;
  const int part = tid >> 6;
  const int sx = p >> 4, sy = (p >> 2) & 3, sz = p & 3;
  const float ptx = linf(bi*4+sx), pty = linf(bj*4+sy), ptz = linf(bk*4+sz);
  float acc = 0.0f;
  for (int c0 = 0; c0 < NG; c0 += CHUNK) {
    if (tid == 0) s_cnt = 0;
    __syncthreads();
    int g = c0 + tid;
    float4 P = posopa[g];
    if (P.w > 0.0f &&
        P.x > vminx && P.x < vmaxx &&
        P.y > vminy && P.y < vmaxy &&
        P.z > vminz && P.z < vmaxz) {
      int slot = atomicAdd(&s_cnt, 1);
      s_g[3*slot+0] = P;
      s_g[3*slot+1] = invrec[2*g+0];
      s_g[3*slot+2] = invrec[2*g+1];
    }
    __syncthreads();
    const int n = s_cnt;
    #pragma unroll 4
    for (int j = part; j < n; j += 8) {
      float4 Pq = s_g[3*j+0];
      float4 I0 = s_g[3*j+1];
      float4 I1 = s_g[3*j+2];
      float px = ptx - Pq.x, py = pty - Pq.y, pz = ptz - Pq.z;
      float power = px*px*I0.x + py*py*I0.w + pz*pz*I1.y
                  + px*py*I0.y + px*pz*I0.z + py*pz*I1.x;
      power = (power > 0.0f) ? -1e10f : power;
      acc += Pq.w * __expf(power);
    }
    __syncthreads();
  }
  s_acc[tid] = acc;
  __syncthreads();
  if (tid < 64) {
    float v = 0.0f;
    #pragma unroll
    for (int w = 0; w < 8; ++w) v += s_acc[tid + w*64];
    out[(bi*4+sx)*4096 + (bj*4+sy)*64 + (bk*4+sz)] = v;
  }
}

extern "C" void kernel_launch(void* const* d_in, const int* in_sizes, int n_in,
                              void* d_out, int out_size, void* d_ws, size_t ws_size,
                              hipStream_t stream) {
  const float* xyz  = (const float*)d_in[0];
  const float* scal = (const float*)d_in[1];
  const float* rot  = (const float*)d_in[2];
  const float* opac = (const float*)d_in[3];
  float* out = (float*)d_out;
  char* ws = (char*)d_ws;
  float4* posopa = (float4*)(ws);                       //  64 KB
  float4* invrec = (float4*)(ws + 65536);               // 128 KB
  int*    bincnt = (int*)(ws + 65536 + 131072);         //  16 KB (4096 bins)
  unsigned short* binidx = (unsigned short*)(ws + 65536 + 131072 + 16384);
  const size_t base = 65536 + 131072 + 16384;

  gm_prep<<<8, 512, 0, stream>>>(xyz, scal, rot, opac, posopa, invrec);

  int cap = 0;  // per-3D-bin capacity tier; 4096 can never overflow
  if      (ws_size >= base + (size_t)4096*4096*2) cap = 4096;
  else if (ws_size >= base + (size_t)4096*2048*2) cap = 2048;  // max real bin ~1.2K

  if (cap) {
    gm_bin3    <<<256, 256, 0, stream>>>(posopa, bincnt, binidx, cap);
    gm_evaluate<<<4096, EV_THREADS, 0, stream>>>(posopa, invrec, bincnt, binidx, cap, out);
  } else {
    gm_evaluate_nobin<<<4096, EV_THREADS, 0, stream>>>(posopa, invrec, out);
  }
}